// Round 5
// baseline (12502.934 us; speedup 1.0000x reference)
//
#include <hip/hip_runtime.h>

#define T_STEPS 512
#define BB 64
#define CC 256
#define HH 1024
#define TBROWS (T_STEPS*BB)      // 32768
#define BH (BB*HH)               // 65536

typedef unsigned short u16;
typedef __bf16 bf16_t;
typedef bf16_t bf16x8 __attribute__((ext_vector_type(8)));
typedef float f32x4 __attribute__((ext_vector_type(4)));

__device__ __forceinline__ f32x4 mfma16(bf16x8 a, bf16x8 b, f32x4 c) {
  return __builtin_amdgcn_mfma_f32_16x16x32_bf16(a, b, c, 0, 0, 0);
}

__device__ __forceinline__ u16 f2bf(float f) {
  unsigned u = __float_as_uint(f);
  u += 0x7fffu + ((u >> 16) & 1u);
  return (u16)(u >> 16);
}
__device__ __forceinline__ float bf2f(u16 h) {
  return __uint_as_float(((unsigned)h) << 16);
}

// coherent 8B store: write-through to LLC (agent coherence point), cross-XCD safe
__device__ __forceinline__ void store_coh8(void* p, uint2 v) {
  asm volatile("global_store_dwordx2 %0, %1, off sc0 sc1" :: "v"(p), "v"(v) : "memory");
}

__global__ void sentinel_kernel(float* o, float v) { o[0] = v; }

// ---------------- split fp32 -> (hi, lo) bf16 ----------------
__global__ __launch_bounds__(256) void split_kernel(const float* __restrict__ src,
                                                    u16* __restrict__ hi,
                                                    u16* __restrict__ lo, int n4) {
  int i = blockIdx.x * 256 + threadIdx.x;
  if (i >= n4) return;
  const float4 v = ((const float4*)src)[i];
  float vv[4] = {v.x, v.y, v.z, v.w};
  u16 h[4], l[4];
#pragma unroll
  for (int j = 0; j < 4; ++j) {
    h[j] = f2bf(vv[j]);
    l[j] = f2bf(vv[j] - bf2f(h[j]));
  }
  uint2 ho, lu;
  ho.x = (unsigned)h[0] | ((unsigned)h[1] << 16);
  ho.y = (unsigned)h[2] | ((unsigned)h[3] << 16);
  lu.x = (unsigned)l[0] | ((unsigned)l[1] << 16);
  lu.y = (unsigned)l[2] | ((unsigned)l[3] << 16);
  ((uint2*)hi)[i] = ho;
  ((uint2*)lo)[i] = lu;
}

__global__ __launch_bounds__(256) void add_bias_kernel(const float* __restrict__ a,
                                                       const float* __restrict__ b,
                                                       float* __restrict__ o, int n) {
  int i = blockIdx.x * 256 + threadIdx.x;
  if (i < n) o[i] = a[i] + b[i];
}

// ---------------- split-bf16 3-pass GEMM: C[M,N] = A[M,K] @ W[N,K]^T + bias ----------------
__global__ __launch_bounds__(256) void gemm3(const u16* __restrict__ Ahi, const u16* __restrict__ Alo,
                                             const u16* __restrict__ Whi, const u16* __restrict__ Wlo,
                                             const float* __restrict__ bias,
                                             float* __restrict__ Cd,
                                             int M, int N, int K) {
  __shared__ u16 As[2][128][48];
  __shared__ u16 Bs[2][128][48];
  const int tid = threadIdx.x;
  const int nblk = N >> 7;
  const int mb = blockIdx.x / nblk;
  const int nb = blockIdx.x % nblk;
  const int m0 = mb << 7, n0 = nb << 7;
  const int lane = tid & 63, wave = tid >> 6;
  const int wm = (wave >> 1) * 64, wn = (wave & 1) * 64;
  const int fr = lane & 15, kg = lane >> 4;

  f32x4 acc[4][4];
#pragma unroll
  for (int i = 0; i < 4; ++i)
#pragma unroll
    for (int j = 0; j < 4; ++j) acc[i][j] = (f32x4){0.f, 0.f, 0.f, 0.f};

  const int sr = tid >> 1;        // 0..127
  const int sk = (tid & 1) * 16;  // 0 or 16

  for (int k0 = 0; k0 < K; k0 += 32) {
    __syncthreads();
    const size_t aoff = (size_t)(m0 + sr) * K + k0 + sk;
    *(uint4*)&As[0][sr][sk]     = *(const uint4*)(Ahi + aoff);
    *(uint4*)&As[0][sr][sk + 8] = *(const uint4*)(Ahi + aoff + 8);
    *(uint4*)&As[1][sr][sk]     = *(const uint4*)(Alo + aoff);
    *(uint4*)&As[1][sr][sk + 8] = *(const uint4*)(Alo + aoff + 8);
    const size_t woff = (size_t)(n0 + sr) * K + k0 + sk;
    *(uint4*)&Bs[0][sr][sk]     = *(const uint4*)(Whi + woff);
    *(uint4*)&Bs[0][sr][sk + 8] = *(const uint4*)(Whi + woff + 8);
    *(uint4*)&Bs[1][sr][sk]     = *(const uint4*)(Wlo + woff);
    *(uint4*)&Bs[1][sr][sk + 8] = *(const uint4*)(Wlo + woff + 8);
    __syncthreads();

    bf16x8 ah[4], al[4], bh[4], bl[4];
#pragma unroll
    for (int i = 0; i < 4; ++i) {
      ah[i] = *(const bf16x8*)&As[0][wm + i * 16 + fr][kg * 8];
      al[i] = *(const bf16x8*)&As[1][wm + i * 16 + fr][kg * 8];
      bh[i] = *(const bf16x8*)&Bs[0][wn + i * 16 + fr][kg * 8];
      bl[i] = *(const bf16x8*)&Bs[1][wn + i * 16 + fr][kg * 8];
    }
#pragma unroll
    for (int i = 0; i < 4; ++i)
#pragma unroll
      for (int j = 0; j < 4; ++j) {
        acc[i][j] = mfma16(ah[i], bh[j], acc[i][j]);
        acc[i][j] = mfma16(ah[i], bl[j], acc[i][j]);
        acc[i][j] = mfma16(al[i], bh[j], acc[i][j]);
      }
  }

#pragma unroll
  for (int j = 0; j < 4; ++j) {
    const int n = n0 + wn + j * 16 + fr;
    const float bv = bias ? bias[n] : 0.f;
#pragma unroll
    for (int i = 0; i < 4; ++i) {
#pragma unroll
      for (int r = 0; r < 4; ++r) {
        const int m = m0 + wm + i * 16 + kg * 4 + r;
        Cd[(size_t)m * N + n] = acc[i][j][r] + bv;
      }
    }
  }
}

// ---------------- persistent RNN scan (one layer, one chunk of nsteps) ----------------
// grid = 64 WGs x 1024 threads (16 waves). WG i owns output cols [16i,16i+16).
// K=1024 split 4 ways across waves: wave = (q,g), q=wave>>2 K-slice, g=wave&3 batch group.
// Per wave: 16 global 16B h-loads + 24 MFMA (vs 64+96 at 4 waves) -> loads fit in
// flight and 4 waves/SIMD interleave the latency (round-4 was 1 wave/SIMD, fully
// serialized). Partials combined in LDS (q=1..3 write, q=0 sums + epilogue).
__global__ __launch_bounds__(1024) void rnn_scan(const u16* __restrict__ Whi, const u16* __restrict__ Wlo,
                                                 const u16* __restrict__ cin_hi, const u16* __restrict__ cin_lo,
                                                 const float* __restrict__ xw,   // [nsteps,B,H]
                                                 u16* __restrict__ yhi, u16* __restrict__ ylo,
                                                 u16* __restrict__ cout_hi, u16* __restrict__ cout_lo,
                                                 float* __restrict__ hlast,      // [B,H] f32
                                                 int* __restrict__ flags,        // [nsteps][64]
                                                 int nsteps) {
  __shared__ u16 Ws[2][16][1024];   // 64 KB, XOR-swizzled rows
  __shared__ f32x4 red[3][4][64];   // 12 KB cross-wave K-reduction
  const int wg = blockIdx.x;
  const int n0 = wg << 4;
  const int tid = threadIdx.x;
  const int lane = tid & 63, wave = tid >> 6;
  const int q = wave >> 2;          // K-slice: k in [q*256, q*256+256)
  const int g = wave & 3;           // batch group
  const int fr = lane & 15, kg = lane >> 4;

  auto wsp = [&](int hl, int r, int cbyte) -> u16* {
    return (u16*)((char*)Ws + (size_t)(hl * 16 + r) * 2048 + (cbyte ^ ((r & 7) << 4)));
  };

  {  // stage W slice with 1024 threads: 64 B per thread
#pragma unroll
    for (int j = 0; j < 4; ++j) {
      const int off = tid * 64 + j * 16;   // byte offset in the 64 KB image
      const int plane = off >> 15;         // 0: hi, 1: lo
      const int row = (off >> 11) & 15;
      const int cbyte = off & 2047;
      const u16* src = (plane ? Wlo : Whi) + (size_t)(n0 + row) * HH + (cbyte >> 1);
      *(uint4*)wsp(plane, row, cbyte) = *(const uint4*)src;
    }
  }
  __syncthreads();

  const int b = (g << 4) + fr;                     // batch (B-operand col, output col)
  const int co = n0 + (kg << 2);                   // output column base (4 contiguous)
  const size_t hoff = (size_t)b * HH + q * 256 + (kg << 3);  // this wave's K-slice base

  for (int t = 0; t < nsteps; ++t) {
    const size_t obase = (size_t)t * BH;
    float4 xwv;
    if (q == 0) xwv = *(const float4*)(xw + obase + (size_t)b * HH + co);  // flag-independent

    if (t > 0) {
      if (tid < 64) {
        const int* f = flags + (t - 1) * 64 + tid;
        while (__hip_atomic_load(f, __ATOMIC_RELAXED, __HIP_MEMORY_SCOPE_AGENT) == 0) {
          __builtin_amdgcn_s_sleep(1);
        }
      }
      __syncthreads();                      // barrier A
      __atomic_signal_fence(__ATOMIC_ACQUIRE);
    }

    const u16* hh = (t == 0) ? cin_hi : (yhi + (size_t)(t - 1) * BH);
    const u16* hl = (t == 0) ? cin_lo : (ylo + (size_t)(t - 1) * BH);
    const u16* pb = hh + hoff;
    const u16* pl = hl + hoff;

    f32x4 accs[3][2];
#pragma unroll
    for (int i = 0; i < 3; ++i)
#pragma unroll
      for (int j = 0; j < 2; ++j) accs[i][j] = (f32x4){0.f, 0.f, 0.f, 0.f};

#pragma unroll
    for (int kc = 0; kc < 8; ++kc) {
      const int cb = q * 512 + kc * 64 + kg * 16;  // byte offset of W fragment in row
      bf16x8 hb  = *(const bf16x8*)(pb + kc * 32);
      bf16x8 hlv = *(const bf16x8*)(pl + kc * 32);
      bf16x8 wh = *(const bf16x8*)wsp(0, fr, cb);
      bf16x8 wl = *(const bf16x8*)wsp(1, fr, cb);
      const int s = kc & 1;
      accs[0][s] = mfma16(wh, hb,  accs[0][s]);   // Whi * h_hi
      accs[1][s] = mfma16(wh, hlv, accs[1][s]);   // Whi * h_lo
      accs[2][s] = mfma16(wl, hb,  accs[2][s]);   // Wlo * h_hi
    }
    f32x4 accv = (accs[0][0] + accs[0][1]) + (accs[1][0] + accs[1][1]) +
                 (accs[2][0] + accs[2][1]);

    if (q != 0) red[q - 1][g][lane] = accv;       // written between A(t) and B(t)
    __syncthreads();                              // barrier B

    if (q == 0) {
      accv = accv + red[0][g][lane] + red[1][g][lane] + red[2][g][lane];

      u16 hbv[4], lbv[4];
      float hv[4];
#pragma unroll
      for (int r = 0; r < 4; ++r) {
        const float s = accv[r] + ((const float*)&xwv)[r];
        hv[r] = tanhf(s);
        hbv[r] = f2bf(hv[r]);
        lbv[r] = f2bf(hv[r] - bf2f(hbv[r]));
      }
      const size_t oi = obase + (size_t)b * HH + co;
      uint2 hp, lp;
      hp.x = (unsigned)hbv[0] | ((unsigned)hbv[1] << 16);
      hp.y = (unsigned)hbv[2] | ((unsigned)hbv[3] << 16);
      lp.x = (unsigned)lbv[0] | ((unsigned)lbv[1] << 16);
      lp.y = (unsigned)lbv[2] | ((unsigned)lbv[3] << 16);
      store_coh8(yhi + oi, hp);
      store_coh8(ylo + oi, lp);
      if (t == nsteps - 1) {
        const size_t ci = (size_t)b * HH + co;
        *(uint2*)(cout_hi + ci) = hp;
        *(uint2*)(cout_lo + ci) = lp;
        *(float4*)(hlast + ci) = (float4){hv[0], hv[1], hv[2], hv[3]};
      }
      asm volatile("s_waitcnt vmcnt(0)" ::: "memory");  // y stores reached LLC
    }
    __syncthreads();                              // barrier C
    if (tid == 0)
      __hip_atomic_store(flags + t * 64 + wg, 1, __ATOMIC_RELEASE, __HIP_MEMORY_SCOPE_AGENT);
  }
}

// ---------------- host ----------------
struct Ptrs {
  u16 *wih0_hi, *wih0_lo, *whh0_hi, *whh0_lo, *wih1_hi, *wih1_lo,
      *whh1_hi, *whh1_lo, *wdec_hi, *wdec_lo;
  float *b0, *b1;
  u16 *carA_hi, *carA_lo, *carB_hi, *carB_lo;  // [2*BH] each (layer0 at 0, layer1 at +BH)
  int* flags;                                   // [2*T_STEPS*64]
  u16 *x_hi, *x_lo;                             // [CT*BB*CC]
  float* xw;                                    // [CT*BH]
  u16 *y_hi, *y_lo;                             // [CT*BH]
  size_t total;
};

static Ptrs make_plan(char* base, int CT) {
  Ptrs p;
  size_t off = 0;
  auto take = [&](size_t bytes) -> char* {
    off = (off + 255) & ~(size_t)255;
    char* q = base + off;
    off += bytes;
    return q;
  };
  p.wih0_hi = (u16*)take((size_t)HH * CC * 2);
  p.wih0_lo = (u16*)take((size_t)HH * CC * 2);
  p.whh0_hi = (u16*)take((size_t)HH * HH * 2);
  p.whh0_lo = (u16*)take((size_t)HH * HH * 2);
  p.wih1_hi = (u16*)take((size_t)HH * HH * 2);
  p.wih1_lo = (u16*)take((size_t)HH * HH * 2);
  p.whh1_hi = (u16*)take((size_t)HH * HH * 2);
  p.whh1_lo = (u16*)take((size_t)HH * HH * 2);
  p.wdec_hi = (u16*)take((size_t)CC * HH * 2);
  p.wdec_lo = (u16*)take((size_t)CC * HH * 2);
  p.b0      = (float*)take((size_t)HH * 4);
  p.b1      = (float*)take((size_t)HH * 4);
  p.carA_hi = (u16*)take((size_t)2 * BH * 2);
  p.carA_lo = (u16*)take((size_t)2 * BH * 2);
  p.carB_hi = (u16*)take((size_t)2 * BH * 2);
  p.carB_lo = (u16*)take((size_t)2 * BH * 2);
  p.flags   = (int*)take((size_t)2 * T_STEPS * 64 * 4);
  p.x_hi    = (u16*)take((size_t)CT * BB * CC * 2);
  p.x_lo    = (u16*)take((size_t)CT * BB * CC * 2);
  p.xw      = (float*)take((size_t)CT * BH * 4);
  p.y_hi    = (u16*)take((size_t)CT * BH * 2);
  p.y_lo    = (u16*)take((size_t)CT * BH * 2);
  p.total   = off;
  return p;
}

extern "C" void kernel_launch(void* const* d_in, const int* in_sizes, int n_in,
                              void* d_out, int out_size, void* d_ws, size_t ws_size,
                              hipStream_t stream) {
  (void)in_sizes; (void)n_in; (void)out_size;
  const float* x     = (const float*)d_in[0];
  const float* h0    = (const float*)d_in[1];
  const float* w_ih0 = (const float*)d_in[2];
  const float* w_hh0 = (const float*)d_in[3];
  const float* b_ih0 = (const float*)d_in[4];
  const float* b_hh0 = (const float*)d_in[5];
  const float* w_ih1 = (const float*)d_in[6];
  const float* w_hh1 = (const float*)d_in[7];
  const float* b_ih1 = (const float*)d_in[8];
  const float* b_hh1 = (const float*)d_in[9];
  const float* w_dec = (const float*)d_in[10];
  const float* b_dec = (const float*)d_in[11];
  float* out = (float*)d_out;

  // largest chunk CT (timesteps) whose plan fits ws_size
  int CT = T_STEPS;
  Ptrs P = make_plan((char*)d_ws, CT);
  while (P.total > ws_size && CT > 8) {
    CT >>= 1;
    P = make_plan((char*)d_ws, CT);
  }
  if (P.total > ws_size) {
    // diagnostic: reported absmax ~= ws_size in bytes
    sentinel_kernel<<<1, 1, 0, stream>>>(out, (float)ws_size);
    return;
  }
  const int NCH = T_STEPS / CT;

  hipMemsetAsync(P.flags, 0, (size_t)2 * T_STEPS * 64 * 4, stream);

  // one-time weight/bias/h0 prep
  split_kernel<<<HH * CC / 1024, 256, 0, stream>>>(w_ih0, P.wih0_hi, P.wih0_lo, HH * CC / 4);
  split_kernel<<<HH * HH / 1024, 256, 0, stream>>>(w_hh0, P.whh0_hi, P.whh0_lo, HH * HH / 4);
  split_kernel<<<HH * HH / 1024, 256, 0, stream>>>(w_ih1, P.wih1_hi, P.wih1_lo, HH * HH / 4);
  split_kernel<<<HH * HH / 1024, 256, 0, stream>>>(w_hh1, P.whh1_hi, P.whh1_lo, HH * HH / 4);
  split_kernel<<<CC * HH / 1024, 256, 0, stream>>>(w_dec, P.wdec_hi, P.wdec_lo, CC * HH / 4);
  split_kernel<<<2 * BH / 1024, 256, 0, stream>>>(h0, P.carA_hi, P.carA_lo, 2 * BH / 4);
  add_bias_kernel<<<HH / 256, 256, 0, stream>>>(b_ih0, b_hh0, P.b0, HH);
  add_bias_kernel<<<HH / 256, 256, 0, stream>>>(b_ih1, b_hh1, P.b1, HH);

  float* hlast0 = out + (size_t)TBROWS * CC;
  float* hlast1 = hlast0 + BH;

  for (int c = 0; c < NCH; ++c) {
    const int t0 = c * CT;
    const u16* cin_hi = (c & 1) ? P.carB_hi : P.carA_hi;
    const u16* cin_lo = (c & 1) ? P.carB_lo : P.carA_lo;
    u16* cout_hi = (c & 1) ? P.carA_hi : P.carB_hi;
    u16* cout_lo = (c & 1) ? P.carA_lo : P.carB_lo;

    // split x chunk
    split_kernel<<<CT * 16, 256, 0, stream>>>(x + (size_t)t0 * BB * CC, P.x_hi, P.x_lo,
                                              CT * BB * CC / 4);
    // layer-0 input projection: [CT*64, 256] @ [1024,256]^T -> xw
    gemm3<<<(CT * BB / 128) * (HH / 128), 256, 0, stream>>>(P.x_hi, P.x_lo, P.wih0_hi, P.wih0_lo,
                                                            P.b0, P.xw, CT * BB, HH, CC);
    // layer-0 scan
    rnn_scan<<<64, 1024, 0, stream>>>(P.whh0_hi, P.whh0_lo, cin_hi, cin_lo, P.xw, P.y_hi, P.y_lo,
                                      cout_hi, cout_lo, hlast0,
                                      P.flags + (size_t)t0 * 64, CT);
    // layer-1 input projection (xw overwrite ok): [CT*64,1024] @ [1024,1024]^T
    gemm3<<<(CT * BB / 128) * (HH / 128), 256, 0, stream>>>(P.y_hi, P.y_lo, P.wih1_hi, P.wih1_lo,
                                                            P.b1, P.xw, CT * BB, HH, HH);
    // layer-1 scan (y overwrite ok)
    rnn_scan<<<64, 1024, 0, stream>>>(P.whh1_hi, P.whh1_lo, cin_hi + BH, cin_lo + BH, P.xw,
                                      P.y_hi, P.y_lo, cout_hi + BH, cout_lo + BH, hlast1,
                                      P.flags + (size_t)(T_STEPS + t0) * 64, CT);
    // decoder: [CT*64,1024] @ [256,1024]^T -> out chunk
    gemm3<<<(CT * BB / 128) * (CC / 128), 256, 0, stream>>>(P.y_hi, P.y_lo, P.wdec_hi, P.wdec_lo,
                                                            b_dec, out + (size_t)t0 * BB * CC,
                                                            CT * BB, CC, HH);
  }
}

// Round 6
// 10065.740 us; speedup vs baseline: 1.2421x; 1.2421x over previous
//
#include <hip/hip_runtime.h>

#define T_STEPS 512
#define BB 64
#define CC 256
#define HH 1024
#define TBROWS (T_STEPS*BB)      // 32768
#define BH (BB*HH)               // 65536

typedef unsigned short u16;
typedef __bf16 bf16_t;
typedef bf16_t bf16x8 __attribute__((ext_vector_type(8)));
typedef float f32x4 __attribute__((ext_vector_type(4)));

__device__ __forceinline__ f32x4 mfma16(bf16x8 a, bf16x8 b, f32x4 c) {
  return __builtin_amdgcn_mfma_f32_16x16x32_bf16(a, b, c, 0, 0, 0);
}

__device__ __forceinline__ u16 f2bf(float f) {
  unsigned u = __float_as_uint(f);
  u += 0x7fffu + ((u >> 16) & 1u);
  return (u16)(u >> 16);
}
__device__ __forceinline__ float bf2f(u16 h) {
  return __uint_as_float(((unsigned)h) << 16);
}

// coherent 8B store: write-through to LLC (agent coherence point), cross-XCD safe
__device__ __forceinline__ void store_coh8(void* p, uint2 v) {
  asm volatile("global_store_dwordx2 %0, %1, off sc0 sc1" :: "v"(p), "v"(v) : "memory");
}

__global__ void sentinel_kernel(float* o, float v) { o[0] = v; }

// ---------------- split fp32 -> (hi, lo) bf16 ----------------
__global__ __launch_bounds__(256) void split_kernel(const float* __restrict__ src,
                                                    u16* __restrict__ hi,
                                                    u16* __restrict__ lo, int n4) {
  int i = blockIdx.x * 256 + threadIdx.x;
  if (i >= n4) return;
  const float4 v = ((const float4*)src)[i];
  float vv[4] = {v.x, v.y, v.z, v.w};
  u16 h[4], l[4];
#pragma unroll
  for (int j = 0; j < 4; ++j) {
    h[j] = f2bf(vv[j]);
    l[j] = f2bf(vv[j] - bf2f(h[j]));
  }
  uint2 ho, lu;
  ho.x = (unsigned)h[0] | ((unsigned)h[1] << 16);
  ho.y = (unsigned)h[2] | ((unsigned)h[3] << 16);
  lu.x = (unsigned)l[0] | ((unsigned)l[1] << 16);
  lu.y = (unsigned)l[2] | ((unsigned)l[3] << 16);
  ((uint2*)hi)[i] = ho;
  ((uint2*)lo)[i] = lu;
}

__global__ __launch_bounds__(256) void add_bias_kernel(const float* __restrict__ a,
                                                       const float* __restrict__ b,
                                                       float* __restrict__ o, int n) {
  int i = blockIdx.x * 256 + threadIdx.x;
  if (i < n) o[i] = a[i] + b[i];
}

// ---------------- split-bf16 3-pass GEMM: C[M,N] = A[M,K] @ W[N,K]^T + bias ----------------
__global__ __launch_bounds__(256) void gemm3(const u16* __restrict__ Ahi, const u16* __restrict__ Alo,
                                             const u16* __restrict__ Whi, const u16* __restrict__ Wlo,
                                             const float* __restrict__ bias,
                                             float* __restrict__ Cd,
                                             int M, int N, int K) {
  __shared__ u16 As[2][128][48];
  __shared__ u16 Bs[2][128][48];
  const int tid = threadIdx.x;
  const int nblk = N >> 7;
  const int mb = blockIdx.x / nblk;
  const int nb = blockIdx.x % nblk;
  const int m0 = mb << 7, n0 = nb << 7;
  const int lane = tid & 63, wave = tid >> 6;
  const int wm = (wave >> 1) * 64, wn = (wave & 1) * 64;
  const int fr = lane & 15, kg = lane >> 4;

  f32x4 acc[4][4];
#pragma unroll
  for (int i = 0; i < 4; ++i)
#pragma unroll
    for (int j = 0; j < 4; ++j) acc[i][j] = (f32x4){0.f, 0.f, 0.f, 0.f};

  const int sr = tid >> 1;        // 0..127
  const int sk = (tid & 1) * 16;  // 0 or 16

  for (int k0 = 0; k0 < K; k0 += 32) {
    __syncthreads();
    const size_t aoff = (size_t)(m0 + sr) * K + k0 + sk;
    *(uint4*)&As[0][sr][sk]     = *(const uint4*)(Ahi + aoff);
    *(uint4*)&As[0][sr][sk + 8] = *(const uint4*)(Ahi + aoff + 8);
    *(uint4*)&As[1][sr][sk]     = *(const uint4*)(Alo + aoff);
    *(uint4*)&As[1][sr][sk + 8] = *(const uint4*)(Alo + aoff + 8);
    const size_t woff = (size_t)(n0 + sr) * K + k0 + sk;
    *(uint4*)&Bs[0][sr][sk]     = *(const uint4*)(Whi + woff);
    *(uint4*)&Bs[0][sr][sk + 8] = *(const uint4*)(Whi + woff + 8);
    *(uint4*)&Bs[1][sr][sk]     = *(const uint4*)(Wlo + woff);
    *(uint4*)&Bs[1][sr][sk + 8] = *(const uint4*)(Wlo + woff + 8);
    __syncthreads();

    bf16x8 ah[4], al[4], bh[4], bl[4];
#pragma unroll
    for (int i = 0; i < 4; ++i) {
      ah[i] = *(const bf16x8*)&As[0][wm + i * 16 + fr][kg * 8];
      al[i] = *(const bf16x8*)&As[1][wm + i * 16 + fr][kg * 8];
      bh[i] = *(const bf16x8*)&Bs[0][wn + i * 16 + fr][kg * 8];
      bl[i] = *(const bf16x8*)&Bs[1][wn + i * 16 + fr][kg * 8];
    }
#pragma unroll
    for (int i = 0; i < 4; ++i)
#pragma unroll
      for (int j = 0; j < 4; ++j) {
        acc[i][j] = mfma16(ah[i], bh[j], acc[i][j]);
        acc[i][j] = mfma16(ah[i], bl[j], acc[i][j]);
        acc[i][j] = mfma16(al[i], bh[j], acc[i][j]);
      }
  }

#pragma unroll
  for (int j = 0; j < 4; ++j) {
    const int n = n0 + wn + j * 16 + fr;
    const float bv = bias ? bias[n] : 0.f;
#pragma unroll
    for (int i = 0; i < 4; ++i) {
#pragma unroll
      for (int r = 0; r < 4; ++r) {
        const int m = m0 + wm + i * 16 + kg * 4 + r;
        Cd[(size_t)m * N + n] = acc[i][j][r] + bv;
      }
    }
  }
}

// ---------------- fused two-layer pipelined scan ----------------
// 128 WGs x 1024 threads (16 waves = 4 K-slices x 4 batch groups), all co-resident
// (140KB LDS -> 1 WG/CU, 128 <= 256 CUs). wg<64: layer 0 (K=1024, W_hh0).
// wg>=64: layer 1 (K=2048 = [W_ih1 | W_hh1]), consumes y0[t] (flagged) + y1[t-1].
// Per-wave fine polling: wave q waits only on the producer WGs of its K-slice.
// Sync protocol (proven r3-r5): sc0/sc1 write-through y stores + vmcnt(0) before
// release-scope flag store; consumers poll relaxed (first-touch reads are coherent).
__global__ __launch_bounds__(1024) void rnn_fused(
    const u16* __restrict__ whh0_hi, const u16* __restrict__ whh0_lo,
    const u16* __restrict__ wih1_hi, const u16* __restrict__ wih1_lo,
    const u16* __restrict__ whh1_hi, const u16* __restrict__ whh1_lo,
    const u16* __restrict__ cin_hi, const u16* __restrict__ cin_lo,    // [2*BH]
    u16* __restrict__ cout_hi, u16* __restrict__ cout_lo,              // [2*BH]
    const float* __restrict__ xw,                                      // [nsteps,B,H] (b0 included)
    const float* __restrict__ b1,                                      // [H] = b_ih1+b_hh1
    u16* __restrict__ y0hi, u16* __restrict__ y0lo,                    // [nsteps,B,H]
    u16* __restrict__ y1hi, u16* __restrict__ y1lo,                    // [nsteps,B,H]
    float* __restrict__ hlast0, float* __restrict__ hlast1,            // [B,H] f32
    int* __restrict__ flags0, int* __restrict__ flags1,                // [nsteps][64] each
    int nsteps) {
  __shared__ u16 Ws[2][16][2048];   // 128 KB (L0 uses k<1024 of each row)
  __shared__ f32x4 red[3][4][64];   // 12 KB cross-wave K-reduction

  const int wg = blockIdx.x;
  const bool isL1 = wg >= 64;
  const int wl = isL1 ? wg - 64 : wg;
  const int n0 = wl << 4;
  const int tid = threadIdx.x;
  const int lane = tid & 63, wave = tid >> 6;
  const int q = wave >> 2;          // K-slice index
  const int g = wave & 3;           // batch group
  const int fr = lane & 15, kg = lane >> 4;

  // swizzled LDS address: row stride 4096B, XOR 16B slot with (row&7)
  auto wsp = [&](int hl, int r, int cbyte) -> u16* {
    return (u16*)((char*)Ws + (size_t)(hl * 16 + r) * 4096 + (cbyte ^ ((r & 7) << 4)));
  };

  if (!isL1) {  // stage 64KB: [2][16][1024] from whh0
#pragma unroll
    for (int j = 0; j < 4; ++j) {
      const int off = tid * 64 + j * 16;
      const int plane = off >> 15;
      const int row = (off >> 11) & 15;
      const int cbyte = off & 2047;
      const u16* src = (plane ? whh0_lo : whh0_hi) + (size_t)(n0 + row) * HH + (cbyte >> 1);
      *(uint4*)wsp(plane, row, cbyte) = *(const uint4*)src;
    }
  } else {      // stage 128KB: [2][16][2048], k<1024 from wih1, k>=1024 from whh1
#pragma unroll
    for (int j = 0; j < 8; ++j) {
      const int off = tid * 128 + j * 16;
      const int plane = off >> 16;
      const int row = (off >> 12) & 15;
      const int cbyte = off & 4095;
      const int k = cbyte >> 1;
      const u16* src = (k < 1024)
          ? ((plane ? wih1_lo : wih1_hi) + (size_t)(n0 + row) * HH + k)
          : ((plane ? whh1_lo : whh1_hi) + (size_t)(n0 + row) * HH + (k - 1024));
      *(uint4*)wsp(plane, row, cbyte) = *(const uint4*)src;
    }
  }
  __syncthreads();

  const int b = (g << 4) + fr;                   // batch (B-operand col, output col)
  const int co = n0 + (kg << 2);                 // output column base (4 contiguous)
  const int koff = isL1 ? ((q < 2) ? q * 512 : (q - 2) * 512) : q * 256;  // src h col base
  const size_t hoff = (size_t)b * HH + koff + (kg << 3);
  const int nkc = isL1 ? 16 : 8;                 // 32-K chunks per wave
  const int cb0 = isL1 ? q * 1024 : q * 512;     // LDS row byte base of this K-slice
  float4 bias4;
  if (isL1 && q == 0) bias4 = *(const float4*)(b1 + co);

  for (int t = 0; t < nsteps; ++t) {
    const size_t obase = (size_t)t * BH;
    float4 xwv;
    if (!isL1 && q == 0) xwv = *(const float4*)(xw + obase + (size_t)b * HH + co);

    // ---- per-wave fine-grained poll ----
    if (!isL1) {
      if (t > 0 && lane < 16) {
        const int* f = flags0 + (t - 1) * 64 + 16 * q + lane;
        while (__hip_atomic_load(f, __ATOMIC_RELAXED, __HIP_MEMORY_SCOPE_AGENT) == 0)
          __builtin_amdgcn_s_sleep(1);
      }
    } else if (q < 2) {
      if (lane < 32) {
        const int* f = flags0 + t * 64 + 32 * q + lane;
        while (__hip_atomic_load(f, __ATOMIC_RELAXED, __HIP_MEMORY_SCOPE_AGENT) == 0)
          __builtin_amdgcn_s_sleep(1);
      }
    } else {
      if (t > 0 && lane < 32) {
        const int* f = flags1 + (t - 1) * 64 + 32 * (q - 2) + lane;
        while (__hip_atomic_load(f, __ATOMIC_RELAXED, __HIP_MEMORY_SCOPE_AGENT) == 0)
          __builtin_amdgcn_s_sleep(1);
      }
    }
    __atomic_signal_fence(__ATOMIC_ACQUIRE);  // compiler barrier; HW coherent via first-touch

    // ---- source pointers for this wave's K-slice ----
    const u16 *pb, *pl;
    if (!isL1) {
      const u16* hh = (t == 0) ? cin_hi : (y0hi + (size_t)(t - 1) * BH);
      const u16* hl = (t == 0) ? cin_lo : (y0lo + (size_t)(t - 1) * BH);
      pb = hh + hoff; pl = hl + hoff;
    } else if (q < 2) {
      pb = y0hi + obase + hoff; pl = y0lo + obase + hoff;
    } else {
      const u16* hh = (t == 0) ? (cin_hi + BH) : (y1hi + (size_t)(t - 1) * BH);
      const u16* hl = (t == 0) ? (cin_lo + BH) : (y1lo + (size_t)(t - 1) * BH);
      pb = hh + hoff; pl = hl + hoff;
    }

    f32x4 accs[3][2];
#pragma unroll
    for (int i = 0; i < 3; ++i)
#pragma unroll
      for (int j = 0; j < 2; ++j) accs[i][j] = (f32x4){0.f, 0.f, 0.f, 0.f};

    if (!isL1) {
#pragma unroll
      for (int kc = 0; kc < 8; ++kc) {
        const int cb = cb0 + kc * 64 + kg * 16;
        bf16x8 hb  = *(const bf16x8*)(pb + kc * 32);
        bf16x8 hlv = *(const bf16x8*)(pl + kc * 32);
        bf16x8 wh = *(const bf16x8*)wsp(0, fr, cb);
        bf16x8 wl = *(const bf16x8*)wsp(1, fr, cb);
        const int s = kc & 1;
        accs[0][s] = mfma16(wh, hb,  accs[0][s]);
        accs[1][s] = mfma16(wh, hlv, accs[1][s]);
        accs[2][s] = mfma16(wl, hb,  accs[2][s]);
      }
    } else {
#pragma unroll
      for (int kc = 0; kc < 16; ++kc) {
        const int cb = cb0 + kc * 64 + kg * 16;
        bf16x8 hb  = *(const bf16x8*)(pb + kc * 32);
        bf16x8 hlv = *(const bf16x8*)(pl + kc * 32);
        bf16x8 wh = *(const bf16x8*)wsp(0, fr, cb);
        bf16x8 wl = *(const bf16x8*)wsp(1, fr, cb);
        const int s = kc & 1;
        accs[0][s] = mfma16(wh, hb,  accs[0][s]);
        accs[1][s] = mfma16(wh, hlv, accs[1][s]);
        accs[2][s] = mfma16(wl, hb,  accs[2][s]);
      }
    }
    f32x4 accv = (accs[0][0] + accs[0][1]) + (accs[1][0] + accs[1][1]) +
                 (accs[2][0] + accs[2][1]);

    if (q != 0) red[q - 1][g][lane] = accv;
    __syncthreads();                              // barrier B

    if (q == 0) {
      accv = accv + red[0][g][lane] + red[1][g][lane] + red[2][g][lane];
      u16 hbv[4], lbv[4];
      float hv[4];
#pragma unroll
      for (int r = 0; r < 4; ++r) {
        const float s = accv[r] + (isL1 ? ((const float*)&bias4)[r] : ((const float*)&xwv)[r]);
        hv[r] = tanhf(s);
        hbv[r] = f2bf(hv[r]);
        lbv[r] = f2bf(hv[r] - bf2f(hbv[r]));
      }
      const size_t oi = obase + (size_t)b * HH + co;
      uint2 hp, lp;
      hp.x = (unsigned)hbv[0] | ((unsigned)hbv[1] << 16);
      hp.y = (unsigned)hbv[2] | ((unsigned)hbv[3] << 16);
      lp.x = (unsigned)lbv[0] | ((unsigned)lbv[1] << 16);
      lp.y = (unsigned)lbv[2] | ((unsigned)lbv[3] << 16);
      if (!isL1) { store_coh8(y0hi + oi, hp); store_coh8(y0lo + oi, lp); }
      else       { store_coh8(y1hi + oi, hp); store_coh8(y1lo + oi, lp); }
      if (t == nsteps - 1) {
        const size_t ci = (size_t)b * HH + co;
        const size_t cofs = isL1 ? (size_t)BH : 0;
        *(uint2*)(cout_hi + cofs + ci) = hp;
        *(uint2*)(cout_lo + cofs + ci) = lp;
        *(float4*)((isL1 ? hlast1 : hlast0) + ci) = (float4){hv[0], hv[1], hv[2], hv[3]};
      }
      asm volatile("s_waitcnt vmcnt(0)" ::: "memory");  // y stores reached LLC
    }
    __syncthreads();                              // barrier C
    if (tid == 0) {
      int* fp = (isL1 ? flags1 : flags0) + t * 64 + wl;
      __hip_atomic_store(fp, 1, __ATOMIC_RELEASE, __HIP_MEMORY_SCOPE_AGENT);
    }
  }
}

// ---------------- host ----------------
struct Ptrs {
  u16 *wih0_hi, *wih0_lo, *whh0_hi, *whh0_lo, *wih1_hi, *wih1_lo,
      *whh1_hi, *whh1_lo, *wdec_hi, *wdec_lo;
  float *b0, *b1;
  u16 *carA_hi, *carA_lo, *carB_hi, *carB_lo;  // [2*BH] each
  int* flags;                                   // [2*T_STEPS*64]
  u16 *x_hi, *x_lo;                             // [CT*BB*CC]
  float* xw;                                    // [CT*BH]
  u16 *y0_hi, *y0_lo, *y1_hi, *y1_lo;           // [CT*BH]
  size_t total;
};

static Ptrs make_plan(char* base, int CT) {
  Ptrs p;
  size_t off = 0;
  auto take = [&](size_t bytes) -> char* {
    off = (off + 255) & ~(size_t)255;
    char* q = base + off;
    off += bytes;
    return q;
  };
  p.wih0_hi = (u16*)take((size_t)HH * CC * 2);
  p.wih0_lo = (u16*)take((size_t)HH * CC * 2);
  p.whh0_hi = (u16*)take((size_t)HH * HH * 2);
  p.whh0_lo = (u16*)take((size_t)HH * HH * 2);
  p.wih1_hi = (u16*)take((size_t)HH * HH * 2);
  p.wih1_lo = (u16*)take((size_t)HH * HH * 2);
  p.whh1_hi = (u16*)take((size_t)HH * HH * 2);
  p.whh1_lo = (u16*)take((size_t)HH * HH * 2);
  p.wdec_hi = (u16*)take((size_t)CC * HH * 2);
  p.wdec_lo = (u16*)take((size_t)CC * HH * 2);
  p.b0      = (float*)take((size_t)HH * 4);
  p.b1      = (float*)take((size_t)HH * 4);
  p.carA_hi = (u16*)take((size_t)2 * BH * 2);
  p.carA_lo = (u16*)take((size_t)2 * BH * 2);
  p.carB_hi = (u16*)take((size_t)2 * BH * 2);
  p.carB_lo = (u16*)take((size_t)2 * BH * 2);
  p.flags   = (int*)take((size_t)2 * T_STEPS * 64 * 4);
  p.x_hi    = (u16*)take((size_t)CT * BB * CC * 2);
  p.x_lo    = (u16*)take((size_t)CT * BB * CC * 2);
  p.xw      = (float*)take((size_t)CT * BH * 4);
  p.y0_hi   = (u16*)take((size_t)CT * BH * 2);
  p.y0_lo   = (u16*)take((size_t)CT * BH * 2);
  p.y1_hi   = (u16*)take((size_t)CT * BH * 2);
  p.y1_lo   = (u16*)take((size_t)CT * BH * 2);
  p.total   = off;
  return p;
}

extern "C" void kernel_launch(void* const* d_in, const int* in_sizes, int n_in,
                              void* d_out, int out_size, void* d_ws, size_t ws_size,
                              hipStream_t stream) {
  (void)in_sizes; (void)n_in; (void)out_size;
  const float* x     = (const float*)d_in[0];
  const float* h0    = (const float*)d_in[1];
  const float* w_ih0 = (const float*)d_in[2];
  const float* w_hh0 = (const float*)d_in[3];
  const float* b_ih0 = (const float*)d_in[4];
  const float* b_hh0 = (const float*)d_in[5];
  const float* w_ih1 = (const float*)d_in[6];
  const float* w_hh1 = (const float*)d_in[7];
  const float* b_ih1 = (const float*)d_in[8];
  const float* b_hh1 = (const float*)d_in[9];
  const float* w_dec = (const float*)d_in[10];
  const float* b_dec = (const float*)d_in[11];
  float* out = (float*)d_out;

  // largest chunk CT whose plan fits ws_size
  int CT = T_STEPS;
  Ptrs P = make_plan((char*)d_ws, CT);
  while (P.total > ws_size && CT > 8) {
    CT >>= 1;
    P = make_plan((char*)d_ws, CT);
  }
  if (P.total > ws_size) {
    sentinel_kernel<<<1, 1, 0, stream>>>(out, (float)ws_size);
    return;
  }
  const int NCH = T_STEPS / CT;

  hipMemsetAsync(P.flags, 0, (size_t)2 * T_STEPS * 64 * 4, stream);

  // one-time weight/bias/h0 prep
  split_kernel<<<HH * CC / 1024, 256, 0, stream>>>(w_ih0, P.wih0_hi, P.wih0_lo, HH * CC / 4);
  split_kernel<<<HH * HH / 1024, 256, 0, stream>>>(w_hh0, P.whh0_hi, P.whh0_lo, HH * HH / 4);
  split_kernel<<<HH * HH / 1024, 256, 0, stream>>>(w_ih1, P.wih1_hi, P.wih1_lo, HH * HH / 4);
  split_kernel<<<HH * HH / 1024, 256, 0, stream>>>(w_hh1, P.whh1_hi, P.whh1_lo, HH * HH / 4);
  split_kernel<<<CC * HH / 1024, 256, 0, stream>>>(w_dec, P.wdec_hi, P.wdec_lo, CC * HH / 4);
  split_kernel<<<2 * BH / 1024, 256, 0, stream>>>(h0, P.carA_hi, P.carA_lo, 2 * BH / 4);
  add_bias_kernel<<<HH / 256, 256, 0, stream>>>(b_ih0, b_hh0, P.b0, HH);
  add_bias_kernel<<<HH / 256, 256, 0, stream>>>(b_ih1, b_hh1, P.b1, HH);

  float* hlast0 = out + (size_t)TBROWS * CC;
  float* hlast1 = hlast0 + BH;

  for (int c = 0; c < NCH; ++c) {
    const int t0 = c * CT;
    const u16* cin_hi = (c & 1) ? P.carB_hi : P.carA_hi;
    const u16* cin_lo = (c & 1) ? P.carB_lo : P.carA_lo;
    u16* cout_hi = (c & 1) ? P.carA_hi : P.carB_hi;
    u16* cout_lo = (c & 1) ? P.carA_lo : P.carB_lo;

    // split x chunk
    split_kernel<<<CT * 16, 256, 0, stream>>>(x + (size_t)t0 * BB * CC, P.x_hi, P.x_lo,
                                              CT * BB * CC / 4);
    // layer-0 input projection: [CT*64, 256] @ [1024,256]^T -> xw (b0 folded in)
    gemm3<<<(CT * BB / 128) * (HH / 128), 256, 0, stream>>>(P.x_hi, P.x_lo, P.wih0_hi, P.wih0_lo,
                                                            P.b0, P.xw, CT * BB, HH, CC);
    // fused two-layer pipelined scan (replaces scan0 + xw1 GEMM + scan1)
    rnn_fused<<<128, 1024, 0, stream>>>(
        P.whh0_hi, P.whh0_lo, P.wih1_hi, P.wih1_lo, P.whh1_hi, P.whh1_lo,
        cin_hi, cin_lo, cout_hi, cout_lo, P.xw, P.b1,
        P.y0_hi, P.y0_lo, P.y1_hi, P.y1_lo, hlast0, hlast1,
        P.flags + (size_t)t0 * 64, P.flags + (size_t)(T_STEPS + t0) * 64, CT);
    // decoder: [CT*64,1024] @ [256,1024]^T -> out chunk
    gemm3<<<(CT * BB / 128) * (CC / 128), 256, 0, stream>>>(P.y1_hi, P.y1_lo, P.wdec_hi, P.wdec_lo,
                                                            b_dec, out + (size_t)t0 * BB * CC,
                                                            CT * BB, CC, HH);
  }
}